// Round 2
// baseline (477.651 us; speedup 1.0000x reference)
//
#include <hip/hip_runtime.h>

#define BL 16384   // B*L
#define LQ 4096    // L

typedef unsigned int uint;
typedef __attribute__((ext_vector_type(8))) short short8;
typedef __attribute__((ext_vector_type(4))) float floatx4;

union F8 { uint u[4]; uint4 u4; short8 s; };

static __device__ __forceinline__ uint f2bf(float f) {
    uint x = __float_as_uint(f);
    x += 0x7fffu + ((x >> 16) & 1u);   // RTNE
    return x >> 16;
}
static __device__ __forceinline__ float bf2f(uint h) { return __uint_as_float(h << 16); }
static __device__ __forceinline__ uint pk(float lo, float hi) {
    return f2bf(lo) | (f2bf(hi) << 16);
}

// Single-instruction RTNE pack of two f32 -> packed bf16x2 (lo in low half).
// Plain VALU op (no TRANS hazard); T12 recipe, HW-verified on gfx950.
static __device__ __forceinline__ uint cvtpk(float lo, float hi) {
    uint r;
    asm("v_cvt_pk_bf16_f32 %0, %1, %2" : "=v"(r) : "v"(lo), "v"(hi));
    return r;
}

// ============ Kernel 1: QKV projection, split-bf16 MFMA (fp32-accurate) ============
// grid (BL/64, 3), block 256. C = x[BL,128] @ W[128,128]; x=xh+xl, W=Wh+Wl;
// C ≈ xh*Wh + xh*Wl + xl*Wh  (drops xl*Wl ~ 2^-18 rel).
// (Exact baseline version — kept bit-identical to the verified 475.8us kernel.)
__global__ __launch_bounds__(256, 4) void qkv_mfma(
    const float* __restrict__ x, const float* __restrict__ Wq,
    const float* __restrict__ Wk, const float* __restrict__ Wv,
    float* __restrict__ qkvb)
{
    __shared__ uint4 wfh[4][8][64];   // hi frags: [ks][Nt][lane]
    __shared__ uint4 wfl[4][8][64];   // lo frags
    const int tid  = threadIdx.x;
    const int lane = tid & 63;
    const int w    = tid >> 6;
    const int q    = lane >> 4;
    const int c    = lane & 15;
    const int proj = blockIdx.y;
    const float* W = (proj == 0) ? Wq : (proj == 1) ? Wk : Wv;
    float* outb = qkvb + (size_t)proj * BL * 128;

    // prepack W -> hi/lo bf16 B-fragments: elem t = W[(ks*32+q*8+t)*128 + Nt*16+c]
    for (int e = tid; e < 32 * 64; e += 256) {
        const int f = e >> 6, ln = e & 63;
        const int ks = f >> 3, Nt = f & 7;
        const int lq = ln >> 4, lc = ln & 15;
        const float* wp = W + (ks * 32 + lq * 8) * 128 + Nt * 16 + lc;
        F8 hi, lo;
        #pragma unroll
        for (int j = 0; j < 4; ++j) {
            const float a = wp[(2 * j) * 128], b = wp[(2 * j + 1) * 128];
            const uint ha = f2bf(a), hb = f2bf(b);
            hi.u[j] = ha | (hb << 16);
            lo.u[j] = pk(a - bf2f(ha), b - bf2f(hb));
        }
        wfh[ks][Nt][ln] = hi.u4;
        wfl[ks][Nt][ln] = lo.u4;
    }
    __syncthreads();

    floatx4 acc[8];
    #pragma unroll
    for (int i = 0; i < 8; ++i) acc[i] = {0.f, 0.f, 0.f, 0.f};

    const int arow = blockIdx.x * 64 + w * 16 + c;   // A-frag row (m = c)
    #pragma unroll
    for (int ks = 0; ks < 4; ++ks) {
        const float* xp = x + arow * 128 + ks * 32 + q * 8;
        const float4 xa = ((const float4*)xp)[0];
        const float4 xb = ((const float4*)xp)[1];
        const float xv[8] = {xa.x, xa.y, xa.z, xa.w, xb.x, xb.y, xb.z, xb.w};
        F8 xh, xl;
        #pragma unroll
        for (int j = 0; j < 4; ++j) {
            const uint ha = f2bf(xv[2 * j]), hb = f2bf(xv[2 * j + 1]);
            xh.u[j] = ha | (hb << 16);
            xl.u[j] = pk(xv[2 * j] - bf2f(ha), xv[2 * j + 1] - bf2f(hb));
        }
        #pragma unroll
        for (int Nt = 0; Nt < 8; ++Nt) {
            F8 wh, wl;
            wh.u4 = wfh[ks][Nt][lane];
            wl.u4 = wfl[ks][Nt][lane];
            acc[Nt] = __builtin_amdgcn_mfma_f32_16x16x32_bf16(xh.s, wh.s, acc[Nt], 0, 0, 0);
            acc[Nt] = __builtin_amdgcn_mfma_f32_16x16x32_bf16(xh.s, wl.s, acc[Nt], 0, 0, 0);
            acc[Nt] = __builtin_amdgcn_mfma_f32_16x16x32_bf16(xl.s, wh.s, acc[Nt], 0, 0, 0);
        }
    }
    // C layout: row = q*4+r, col = c  (per 16x16 tile)
    const int orow = blockIdx.x * 64 + w * 16 + q * 4;
    #pragma unroll
    for (int Nt = 0; Nt < 8; ++Nt)
        #pragma unroll
        for (int r = 0; r < 4; ++r)
            outb[(orow + r) * 128 + Nt * 16 + c] = acc[Nt][r];
}

// ============ Kernel 2: fused neighbor-attention, MFMA ============
// grid BL/4, block 256 (4 waves); one wave per position, no barriers after init.
// GEMM1: H^T[64j x 32k] = Wa0^T (A, LDS frags) * T^T (B, built from global)
// transform via shuffles -> A2 (H) frags
// GEMM2 per N-tile: logits[32k x 16c] = H * Wa1, fused softmax + weighted-V.
// bf16 packing uses v_cvt_pk_bf16_f32 (1 VALU op vs ~10 for manual RTNE).
// exp/div stay as compiler-managed __expf / IEEE divide (TRANS-op inline asm
// was the round-0 correctness failure: stale-register read on v_rcp result).
__global__ __launch_bounds__(256, 4) void attn_mfma(
    const float* __restrict__ pos, const int* __restrict__ nn_idx,
    const float* __restrict__ qb, const float* __restrict__ kb,
    const float* __restrict__ vb, const float* __restrict__ Wa0,
    const float* __restrict__ Wa1, float* __restrict__ out)
{
    __shared__ uint4 wa0f[16][64];   // [Mt1*4+ks][lane]: Wa0^T A-frags
    __shared__ uint4 wa1f[16][64];   // [ks2*8+Nt2][lane]: Wa1 B-frags
    const int tid  = threadIdx.x;
    const int lane = tid & 63;
    const int w    = tid >> 6;
    const int q    = lane >> 4;
    const int c    = lane & 15;

    // Wa0^T frag elem t = Wa0[(ks*32+q*8+t)*64 + Mt1*16+c]
    for (int e = tid; e < 16 * 64; e += 256) {
        const int f = e >> 6, ln = e & 63;
        const int Mt = f >> 2, ks = f & 3;
        const int lq = ln >> 4, lc = ln & 15;
        const float* wp = Wa0 + (ks * 32 + lq * 8) * 64 + Mt * 16 + lc;
        F8 v;
        #pragma unroll
        for (int j = 0; j < 4; ++j) v.u[j] = cvtpk(wp[(2 * j) * 64], wp[(2 * j + 1) * 64]);
        wa0f[f][ln] = v.u4;
    }
    // Wa1 frag elem t = Wa1[(ks2*32+q*8+t)*128 + Nt2*16+c]
    for (int e = tid; e < 16 * 64; e += 256) {
        const int f = e >> 6, ln = e & 63;
        const int ks = f >> 3, Nt = f & 7;
        const int lq = ln >> 4, lc = ln & 15;
        const float* wp = Wa1 + (ks * 32 + lq * 8) * 128 + Nt * 16 + lc;
        F8 v;
        #pragma unroll
        for (int j = 0; j < 4; ++j) v.u[j] = cvtpk(wp[(2 * j) * 128], wp[(2 * j + 1) * 128]);
        wa1f[f][ln] = v.u4;
    }
    __syncthreads();

    const int p     = blockIdx.x * 4 + w;
    const int bbase = (p >> 12) << 12;           // b * L

    const int idx0 = nn_idx[p * 32 + c];         // neighbor c
    const int idx1 = nn_idx[p * 32 + 16 + c];    // neighbor 16+c
    const int r0   = (bbase + idx0) * 128;
    const int r1   = (bbase + idx1) * 128;
    const int pr0  = (p * 32 + c) * 128;
    const int pr1  = pr0 + 16 * 128;

    // ---- GEMM1 ----
    floatx4 acc1[4][2];
    #pragma unroll
    for (int i = 0; i < 4; ++i) { acc1[i][0] = {0.f,0.f,0.f,0.f}; acc1[i][1] = {0.f,0.f,0.f,0.f}; }

    #pragma unroll
    for (int ks = 0; ks < 4; ++ks) {
        const int u0 = ks * 32 + q * 8;
        const float4 qa = *(const float4*)(qb + p * 128 + u0);
        const float4 qc = *(const float4*)(qb + p * 128 + u0 + 4);
        F8 bfrag[2];
        #pragma unroll
        for (int Nt = 0; Nt < 2; ++Nt) {
            const int kr = (Nt == 0 ? r0 : r1) + u0;
            const int pr = (Nt == 0 ? pr0 : pr1) + u0;
            const float4 ka = *(const float4*)(kb + kr);
            const float4 kc = *(const float4*)(kb + kr + 4);
            const float4 pa = *(const float4*)(pos + pr);
            const float4 pc = *(const float4*)(pos + pr + 4);
            const float t0 = qa.x - ka.x + pa.x, t1 = qa.y - ka.y + pa.y;
            const float t2 = qa.z - ka.z + pa.z, t3 = qa.w - ka.w + pa.w;
            const float t4 = qc.x - kc.x + pc.x, t5 = qc.y - kc.y + pc.y;
            const float t6 = qc.z - kc.z + pc.z, t7 = qc.w - kc.w + pc.w;
            bfrag[Nt].u[0] = cvtpk(t0, t1); bfrag[Nt].u[1] = cvtpk(t2, t3);
            bfrag[Nt].u[2] = cvtpk(t4, t5); bfrag[Nt].u[3] = cvtpk(t6, t7);
        }
        #pragma unroll
        for (int Mt = 0; Mt < 4; ++Mt) {
            F8 a1; a1.u4 = wa0f[Mt * 4 + ks][lane];
            acc1[Mt][0] = __builtin_amdgcn_mfma_f32_16x16x32_bf16(a1.s, bfrag[0].s, acc1[Mt][0], 0, 0, 0);
            acc1[Mt][1] = __builtin_amdgcn_mfma_f32_16x16x32_bf16(a1.s, bfrag[1].s, acc1[Mt][1], 0, 0, 0);
        }
    }

    // ---- transform: C1-layout H^T -> A2 (H) fragments, with relu ----
    // dest elem t of frag (Mt2,ks): j = ks*32+q*8+t, src tile Mt1 = 2ks+(q>>1),
    // src lane = c + 16*((q&1)*2 + (t>>2)), src reg = t&3.
    F8 a2[2][2];
    #pragma unroll
    for (int Mt2 = 0; Mt2 < 2; ++Mt2) {
        #pragma unroll
        for (int ks = 0; ks < 2; ++ks) {
            float vv[8];
            #pragma unroll
            for (int t = 0; t < 8; ++t) {
                const int sl = c + 16 * ((q & 1) * 2 + (t >> 2));
                const float vA = __shfl(acc1[2 * ks + 0][Mt2][t & 3], sl, 64);
                const float vB = __shfl(acc1[2 * ks + 1][Mt2][t & 3], sl, 64);
                vv[t] = fmaxf((q < 2) ? vA : vB, 0.f);
            }
            #pragma unroll
            for (int j = 0; j < 4; ++j) a2[Mt2][ks].u[j] = cvtpk(vv[2 * j], vv[2 * j + 1]);
        }
    }

    // ---- per-row (neighbor) base addresses for the weighted-V phase ----
    int vrow[2][4], prow[2][4];
    #pragma unroll
    for (int Mt2 = 0; Mt2 < 2; ++Mt2)
        #pragma unroll
        for (int r = 0; r < 4; ++r) {
            const int knb  = Mt2 * 16 + q * 4 + r;
            const int sidx = __shfl(Mt2 == 0 ? idx0 : idx1, q * 4 + r, 64);
            vrow[Mt2][r] = (bbase + sidx) * 128;
            prow[Mt2][r] = (p * 32 + knb) * 128;
        }

    // ---- GEMM2 + fused softmax + weighted sum, per N-tile (16 cols) ----
    #pragma unroll
    for (int Nt2 = 0; Nt2 < 8; ++Nt2) {
        F8 b0, b1;
        b0.u4 = wa1f[Nt2][lane];        // ks2 = 0
        b1.u4 = wa1f[8 + Nt2][lane];    // ks2 = 1
        floatx4 a2c[2];
        a2c[0] = {0.f,0.f,0.f,0.f}; a2c[1] = {0.f,0.f,0.f,0.f};
        #pragma unroll
        for (int Mt2 = 0; Mt2 < 2; ++Mt2) {
            a2c[Mt2] = __builtin_amdgcn_mfma_f32_16x16x32_bf16(a2[Mt2][0].s, b0.s, a2c[Mt2], 0, 0, 0);
            a2c[Mt2] = __builtin_amdgcn_mfma_f32_16x16x32_bf16(a2[Mt2][1].s, b1.s, a2c[Mt2], 0, 0, 0);
        }
        const int cg = Nt2 * 16 + c;
        float se = 0.f, ov = 0.f;
        #pragma unroll
        for (int Mt2 = 0; Mt2 < 2; ++Mt2)
            #pragma unroll
            for (int r = 0; r < 4; ++r) {
                const float e  = __expf(a2c[Mt2][r]);
                const float vp = vb[vrow[Mt2][r] + cg] + pos[prow[Mt2][r] + cg];
                se += e;
                ov = fmaf(e, vp, ov);
            }
        se += __shfl_xor(se, 16, 64); ov += __shfl_xor(ov, 16, 64);
        se += __shfl_xor(se, 32, 64); ov += __shfl_xor(ov, 32, 64);
        if (q == 0) out[p * 128 + cg] = ov / se;
    }
}

extern "C" void kernel_launch(void* const* d_in, const int* in_sizes, int n_in,
                              void* d_out, int out_size, void* d_ws, size_t ws_size,
                              hipStream_t stream) {
    const float* x    = (const float*)d_in[0];
    const float* pos  = (const float*)d_in[1];
    const int*   nidx = (const int*)  d_in[2];
    const float* Wq   = (const float*)d_in[3];
    const float* Wk   = (const float*)d_in[4];
    const float* Wv   = (const float*)d_in[5];
    const float* Wa0  = (const float*)d_in[6];
    const float* Wa1  = (const float*)d_in[7];
    float* outp = (float*)d_out;

    float* qkvb = (float*)d_ws;   // q | k | v, each BL*128 f32
    const float* qbp = qkvb;
    const float* kbp = qkvb + (size_t)BL * 128;
    const float* vbp = qkvb + (size_t)2 * BL * 128;

    qkv_mfma<<<dim3(BL / 64, 3), 256, 0, stream>>>(x, Wq, Wk, Wv, qkvb);
    attn_mfma<<<BL / 4, 256, 0, stream>>>(pos, nidx, qbp, kbp, vbp, Wa0, Wa1, outp);
}